// Round 1
// baseline (63.948 us; speedup 1.0000x reference)
//
#include <hip/hip_runtime.h>
#include <hip/hip_bf16.h>

#define N_ROWS 262144
#define DIM    64
#define KCB    512

#define BLOCKS 512
#define THREADS 256
#define ITERS  4          // rows per block = ITERS * 128 = 512

typedef __bf16 bf16x8 __attribute__((ext_vector_type(8)));
typedef float  f32x4  __attribute__((ext_vector_type(4)));

__device__ inline float d2(float4 a, float4 b) {
    float dx = a.x - b.x, dy = a.y - b.y, dz = a.z - b.z, dw = a.w - b.w;
    return dx * dx + dy * dy + dz * dz + dw * dw;
}

// ---- kernel 0: wn[k] = 0.5 * ||w_k||^2 -------------------------------------
__global__ void vq_wnorm(const float* __restrict__ cb, float* __restrict__ wn) {
    int k = threadIdx.x;
    if (k < KCB) {
        const float* w = cb + k * DIM;
        float s = 0.f;
        #pragma unroll
        for (int d = 0; d < DIM; ++d) s += w[d] * w[d];
        wn[k] = 0.5f * s;
    }
}

// ---- kernel 1: argmin + gather + loss partials -----------------------------
__global__ __launch_bounds__(THREADS, 2) void vq_main(
    const float* __restrict__ x, const float* __restrict__ cb,
    const float* __restrict__ wn, float* __restrict__ out,
    float* __restrict__ partials)
{
    // codebook as bf16, 16B granules, XOR-swizzled so ds_read_b128 at row
    // stride 128B is conflict-free (2-way max)
    __shared__ bf16x8 cb_sh[KCB * 8];      // 64 KiB
    __shared__ f32x4  wn_sh4[KCB / 4];     // 2 KiB, 16B-aligned
    __shared__ float  red_sh[THREADS];

    const int tid    = threadIdx.x;
    const int lane   = tid & 63;
    const int wave   = tid >> 6;
    const int lane15 = lane & 15;
    const int half   = lane >> 4;          // 0..3

    // ---- stage codebook f32 -> bf16 into LDS (once per block) ----
    for (int fg = tid; fg < KCB * 8; fg += THREADS) {
        int row = fg >> 3, g = fg & 7;
        const float* src = cb + row * DIM + g * 8;
        float4 f0 = *(const float4*)src;
        float4 f1 = *(const float4*)(src + 4);
        bf16x8 v;
        v[0] = (__bf16)f0.x; v[1] = (__bf16)f0.y; v[2] = (__bf16)f0.z; v[3] = (__bf16)f0.w;
        v[4] = (__bf16)f1.x; v[5] = (__bf16)f1.y; v[6] = (__bf16)f1.z; v[7] = (__bf16)f1.w;
        cb_sh[row * 8 + (g ^ (row & 7))] = v;
    }
    for (int i = tid; i < KCB; i += THREADS) ((float*)wn_sh4)[i] = wn[i];
    __syncthreads();

    const int swz_lo = half ^ (lane & 7);        // granule of dims [half*8, +8)
    const int swz_hi = (4 + half) ^ (lane & 7);  // granule of dims [32+half*8, +8)
    float lossAcc = 0.f;

    for (int it = 0; it < ITERS; ++it) {
        const int base  = blockIdx.x * (ITERS * 128) + it * 128 + wave * 32;
        const int row0  = base + lane15;
        const int row1  = row0 + 16;
        const int dbase = half * 8;

        // x fragments: B-operand layout, col = lane&15 (row id), k = half*8+j
        const float* xr0 = x + (size_t)row0 * DIM + dbase;
        float4 x00 = *(const float4*)xr0;
        float4 x01 = *(const float4*)(xr0 + 4);
        float4 x02 = *(const float4*)(xr0 + 32);
        float4 x03 = *(const float4*)(xr0 + 36);
        const float* xr1 = x + (size_t)row1 * DIM + dbase;
        float4 x10 = *(const float4*)xr1;
        float4 x11 = *(const float4*)(xr1 + 4);
        float4 x12 = *(const float4*)(xr1 + 32);
        float4 x13 = *(const float4*)(xr1 + 36);

        bf16x8 b0lo, b0hi, b1lo, b1hi;
        b0lo[0] = (__bf16)x00.x; b0lo[1] = (__bf16)x00.y; b0lo[2] = (__bf16)x00.z; b0lo[3] = (__bf16)x00.w;
        b0lo[4] = (__bf16)x01.x; b0lo[5] = (__bf16)x01.y; b0lo[6] = (__bf16)x01.z; b0lo[7] = (__bf16)x01.w;
        b0hi[0] = (__bf16)x02.x; b0hi[1] = (__bf16)x02.y; b0hi[2] = (__bf16)x02.z; b0hi[3] = (__bf16)x02.w;
        b0hi[4] = (__bf16)x03.x; b0hi[5] = (__bf16)x03.y; b0hi[6] = (__bf16)x03.z; b0hi[7] = (__bf16)x03.w;
        b1lo[0] = (__bf16)x10.x; b1lo[1] = (__bf16)x10.y; b1lo[2] = (__bf16)x10.z; b1lo[3] = (__bf16)x10.w;
        b1lo[4] = (__bf16)x11.x; b1lo[5] = (__bf16)x11.y; b1lo[6] = (__bf16)x11.z; b1lo[7] = (__bf16)x11.w;
        b1hi[0] = (__bf16)x12.x; b1hi[1] = (__bf16)x12.y; b1hi[2] = (__bf16)x12.z; b1hi[3] = (__bf16)x12.w;
        b1hi[4] = (__bf16)x13.x; b1hi[5] = (__bf16)x13.y; b1hi[6] = (__bf16)x13.z; b1hi[7] = (__bf16)x13.w;

        float best0 = 3.4e38f, best1 = 3.4e38f;
        int   bk0 = 0, bk1 = 0;

        #pragma unroll 4
        for (int t = 0; t < 32; ++t) {
            const int arow = t * 16 + lane15;      // codeword row in A-tile
            bf16x8 alo = cb_sh[arow * 8 + swz_lo];
            bf16x8 ahi = cb_sh[arow * 8 + swz_hi];
            f32x4  wnv = wn_sh4[t * 4 + half];

            f32x4 c0 = {0.f, 0.f, 0.f, 0.f};
            c0 = __builtin_amdgcn_mfma_f32_16x16x32_bf16(alo, b0lo, c0, 0, 0, 0);
            c0 = __builtin_amdgcn_mfma_f32_16x16x32_bf16(ahi, b0hi, c0, 0, 0, 0);
            f32x4 c1 = {0.f, 0.f, 0.f, 0.f};
            c1 = __builtin_amdgcn_mfma_f32_16x16x32_bf16(alo, b1lo, c1, 0, 0, 0);
            c1 = __builtin_amdgcn_mfma_f32_16x16x32_bf16(ahi, b1hi, c1, 0, 0, 0);

            // D[row=half*4+r][col=lane15]; score = 0.5||w||^2 - x.w
            #pragma unroll
            for (int r = 0; r < 4; ++r) {
                const int k = t * 16 + half * 4 + r;
                float s0 = wnv[r] - c0[r];
                if (s0 < best0) { best0 = s0; bk0 = k; }
                float s1 = wnv[r] - c1[r];
                if (s1 < best1) { best1 = s1; bk1 = k; }
            }
        }

        // reduce across the 4 lanes holding the same column (x-row)
        #pragma unroll
        for (int off = 16; off < 64; off <<= 1) {
            float s = __shfl_xor(best0, off); int k = __shfl_xor(bk0, off);
            if (s < best0 || (s == best0 && k < bk0)) { best0 = s; bk0 = k; }
            s = __shfl_xor(best1, off); k = __shfl_xor(bk1, off);
            if (s < best1 || (s == best1 && k < bk1)) { best1 = s; bk1 = k; }
        }

        // gather f32 codebook row, write x_out, accumulate loss
        {
            const float* q = cb + (size_t)bk0 * DIM + dbase;
            float4 q0 = *(const float4*)q,        q1 = *(const float4*)(q + 4);
            float4 q2 = *(const float4*)(q + 32), q3 = *(const float4*)(q + 36);
            float* o = out + (size_t)row0 * DIM + dbase;
            *(float4*)o = q0; *(float4*)(o + 4) = q1;
            *(float4*)(o + 32) = q2; *(float4*)(o + 36) = q3;
            lossAcc += d2(q0, x00) + d2(q1, x01) + d2(q2, x02) + d2(q3, x03);
        }
        {
            const float* q = cb + (size_t)bk1 * DIM + dbase;
            float4 q0 = *(const float4*)q,        q1 = *(const float4*)(q + 4);
            float4 q2 = *(const float4*)(q + 32), q3 = *(const float4*)(q + 36);
            float* o = out + (size_t)row1 * DIM + dbase;
            *(float4*)o = q0; *(float4*)(o + 4) = q1;
            *(float4*)(o + 32) = q2; *(float4*)(o + 36) = q3;
            lossAcc += d2(q0, x10) + d2(q1, x11) + d2(q2, x12) + d2(q3, x13);
        }
    }

    // deterministic block reduction of loss partial
    red_sh[tid] = lossAcc;
    __syncthreads();
    #pragma unroll
    for (int s = THREADS / 2; s > 0; s >>= 1) {
        if (tid < s) red_sh[tid] += red_sh[tid + s];
        __syncthreads();
    }
    if (tid == 0) partials[blockIdx.x] = red_sh[0];
}

// ---- kernel 2: final loss reduction ----------------------------------------
__global__ void vq_finalize(const float* __restrict__ partials,
                            float* __restrict__ out_loss) {
    __shared__ float sh[256];
    int t = threadIdx.x;
    sh[t] = partials[t] + partials[t + 256];
    __syncthreads();
    #pragma unroll
    for (int s = 128; s > 0; s >>= 1) {
        if (t < s) sh[t] += sh[t + s];
        __syncthreads();
    }
    // vq_loss = 0.25*mean + mean = 1.25 * sum / (N*D)
    if (t == 0) out_loss[0] = sh[0] * (1.25f / (float)(N_ROWS * DIM));
}

extern "C" void kernel_launch(void* const* d_in, const int* in_sizes, int n_in,
                              void* d_out, int out_size, void* d_ws, size_t ws_size,
                              hipStream_t stream) {
    const float* x  = (const float*)d_in[0];
    const float* cb = (const float*)d_in[1];
    float* out      = (float*)d_out;
    float* wn       = (float*)d_ws;        // KCB floats
    float* partials = wn + KCB;            // BLOCKS floats

    hipLaunchKernelGGL(vq_wnorm, dim3(1), dim3(512), 0, stream, cb, wn);
    hipLaunchKernelGGL(vq_main, dim3(BLOCKS), dim3(THREADS), 0, stream,
                       x, cb, wn, out, partials);
    hipLaunchKernelGGL(vq_finalize, dim3(1), dim3(256), 0, stream,
                       partials, out + (size_t)N_ROWS * DIM);
}

// Round 2
// 45.739 us; speedup vs baseline: 1.3981x; 1.3981x over previous
//
#include <hip/hip_runtime.h>
#include <hip/hip_bf16.h>

#define N_ROWS 262144
#define DIM    64
#define KCB    512

#define BLOCKS  512
#define THREADS 512          // 8 waves; 64 rows per wave; 512 rows per block

typedef __bf16 bf16x8 __attribute__((ext_vector_type(8)));
typedef float  f32x4  __attribute__((ext_vector_type(4)));

__device__ inline float dot4(float4 a) {
    return a.x * a.x + a.y * a.y + a.z * a.z + a.w * a.w;
}

// ---- kernel 0: wn[k] = 1 + 0.5*||w_k||^2 (bias keeps scores positive) ------
__global__ void vq_wnorm(const float* __restrict__ cb, float* __restrict__ wn) {
    int k = threadIdx.x;
    if (k < KCB) {
        const float* w = cb + k * DIM;
        float s = 0.f;
        #pragma unroll
        for (int d = 0; d < DIM; ++d) s += w[d] * w[d];
        wn[k] = 1.0f + 0.5f * s;
    }
}

// ---- kernel 1: argmin + coalesced gather-store + loss ----------------------
__global__ __launch_bounds__(THREADS, 4) void vq_main(
    const float* __restrict__ x, const float* __restrict__ cb,
    const float* __restrict__ wn, float* __restrict__ out,
    float* __restrict__ partials)
{
    // negated codebook as bf16 granules, XOR-swizzled (round-1 measured 0 conflicts)
    __shared__ bf16x8 cb_sh[KCB * 8];      // 64 KiB
    __shared__ f32x4  wn_sh4[KCB / 4];     // 2 KiB
    __shared__ float  red_sh[THREADS];     // 2 KiB

    const int tid    = threadIdx.x;
    const int lane   = tid & 63;
    const int wave   = tid >> 6;
    const int lane15 = lane & 15;
    const int half   = lane >> 4;          // 0..3

    // ---- stage NEGATED codebook f32 -> bf16 into LDS ----
    for (int fg = tid; fg < KCB * 8; fg += THREADS) {
        int row = fg >> 3, g = fg & 7;
        const float* src = cb + row * DIM + g * 8;
        float4 f0 = *(const float4*)src;
        float4 f1 = *(const float4*)(src + 4);
        bf16x8 v;
        v[0] = (__bf16)(-f0.x); v[1] = (__bf16)(-f0.y); v[2] = (__bf16)(-f0.z); v[3] = (__bf16)(-f0.w);
        v[4] = (__bf16)(-f1.x); v[5] = (__bf16)(-f1.y); v[6] = (__bf16)(-f1.z); v[7] = (__bf16)(-f1.w);
        cb_sh[row * 8 + (g ^ (row & 7))] = v;
    }
    for (int i = tid; i < KCB; i += THREADS) ((float*)wn_sh4)[i] = wn[i];

    // ---- load x for 64 rows/wave (4 cols of 16), build B frags + ||x||^2 ----
    const int wrow = blockIdx.x * (8 * 64) + wave * 64;
    bf16x8 blo[4], bhi[4];
    float  xn[4];
    #pragma unroll
    for (int c = 0; c < 4; ++c) {
        const float* xr = x + (size_t)(wrow + c * 16 + lane15) * DIM + half * 8;
        float4 f0 = *(const float4*)xr;
        float4 f1 = *(const float4*)(xr + 4);
        float4 f2 = *(const float4*)(xr + 32);
        float4 f3 = *(const float4*)(xr + 36);
        xn[c] = dot4(f0) + dot4(f1) + dot4(f2) + dot4(f3);
        bf16x8 lo, hi;
        lo[0] = (__bf16)f0.x; lo[1] = (__bf16)f0.y; lo[2] = (__bf16)f0.z; lo[3] = (__bf16)f0.w;
        lo[4] = (__bf16)f1.x; lo[5] = (__bf16)f1.y; lo[6] = (__bf16)f1.z; lo[7] = (__bf16)f1.w;
        hi[0] = (__bf16)f2.x; hi[1] = (__bf16)f2.y; hi[2] = (__bf16)f2.z; hi[3] = (__bf16)f2.w;
        hi[4] = (__bf16)f3.x; hi[5] = (__bf16)f3.y; hi[6] = (__bf16)f3.z; hi[7] = (__bf16)f3.w;
        blo[c] = lo; bhi[c] = hi;
    }
    __syncthreads();

    const int swz_lo = half ^ (lane & 7);
    const int swz_hi = (4 + half) ^ (lane & 7);
    const unsigned halfbits = (unsigned)(half * 4);

    // packed (score | k) running minima, one per col
    unsigned u0 = 0xFFFFFFFFu, u1 = 0xFFFFFFFFu, u2 = 0xFFFFFFFFu, u3 = 0xFFFFFFFFu;

    #pragma unroll 8
    for (int t = 0; t < 32; ++t) {
        const int arow = t * 16 + lane15;
        bf16x8 alo = cb_sh[arow * 8 + swz_lo];
        bf16x8 ahi = cb_sh[arow * 8 + swz_hi];
        f32x4  wnv = wn_sh4[t * 4 + half];
        unsigned* us[4] = {&u0, &u1, &u2, &u3};
        #pragma unroll
        for (int c = 0; c < 4; ++c) {
            // C-init = wn, A = -w  ->  acc[r] = wn[k] - x.w  (the score)
            f32x4 acc = wnv;
            acc = __builtin_amdgcn_mfma_f32_16x16x32_bf16(alo, blo[c], acc, 0, 0, 0);
            acc = __builtin_amdgcn_mfma_f32_16x16x32_bf16(ahi, bhi[c], acc, 0, 0, 0);
            unsigned p0 = (__float_as_uint(acc[0]) & 0xFFFFFE00u) | (unsigned)(t * 16 + 0) | halfbits;
            unsigned p1 = (__float_as_uint(acc[1]) & 0xFFFFFE00u) | (unsigned)(t * 16 + 1) | halfbits;
            unsigned p2 = (__float_as_uint(acc[2]) & 0xFFFFFE00u) | (unsigned)(t * 16 + 2) | halfbits;
            unsigned p3 = (__float_as_uint(acc[3]) & 0xFFFFFE00u) | (unsigned)(t * 16 + 3) | halfbits;
            unsigned a = p0 < p1 ? p0 : p1;
            unsigned b = p2 < p3 ? p2 : p3;
            unsigned m = a < b ? a : b;
            *us[c] = (*us[c] < m) ? *us[c] : m;
        }
    }

    // ---- reduce across the 4 halves sharing a column; decode k, loss -------
    float lossAcc = 0.f;
    int bks[4];
    unsigned uc[4] = {u0, u1, u2, u3};
    #pragma unroll
    for (int c = 0; c < 4; ++c) {
        unsigned v = uc[c];
        unsigned w16 = (unsigned)__shfl_xor((int)v, 16); v = v < w16 ? v : w16;
        unsigned w32 = (unsigned)__shfl_xor((int)v, 32); v = v < w32 ? v : w32;
        float xnf = xn[c];
        xnf += __shfl_xor(xnf, 16);
        xnf += __shfl_xor(xnf, 32);
        bks[c] = (int)(v & 511u);
        float sstar = __uint_as_float(v & 0xFFFFFE00u);   // = 1 + 0.5||q||^2 - x.q
        // ||x-q||^2 = ||x||^2 + 2*(sstar - 1); 4 lanes duplicate -> *0.25
        lossAcc += 0.25f * (xnf + 2.f * (sstar - 1.f));
    }

    // ---- coalesced gather + store: instr j writes 1KB contiguous -----------
    float* outw = out + (size_t)wrow * DIM;
    #pragma unroll
    for (int j = 0; j < 16; ++j) {
        int srcl = (j * 4 + half) & 15;
        int bk   = __shfl(bks[j >> 2], srcl);
        float4 q = *(const float4*)(cb + (size_t)bk * DIM + (lane & 15) * 4);
        *(float4*)(outw + j * 256 + lane * 4) = q;
    }

    // ---- deterministic block reduction of loss partial ----------------------
    red_sh[tid] = lossAcc;
    __syncthreads();
    #pragma unroll
    for (int s = THREADS / 2; s > 0; s >>= 1) {
        if (tid < s) red_sh[tid] += red_sh[tid + s];
        __syncthreads();
    }
    if (tid == 0) partials[blockIdx.x] = red_sh[0];
}

// ---- kernel 2: final loss reduction ----------------------------------------
__global__ void vq_finalize(const float* __restrict__ partials,
                            float* __restrict__ out_loss) {
    __shared__ float sh[256];
    int t = threadIdx.x;
    sh[t] = partials[t] + partials[t + 256];
    __syncthreads();
    #pragma unroll
    for (int s = 128; s > 0; s >>= 1) {
        if (t < s) sh[t] += sh[t + s];
        __syncthreads();
    }
    // vq_loss = 0.25*mean + mean = 1.25 * sum / (N*D)
    if (t == 0) out_loss[0] = sh[0] * (1.25f / (float)(N_ROWS * DIM));
}

extern "C" void kernel_launch(void* const* d_in, const int* in_sizes, int n_in,
                              void* d_out, int out_size, void* d_ws, size_t ws_size,
                              hipStream_t stream) {
    const float* x  = (const float*)d_in[0];
    const float* cb = (const float*)d_in[1];
    float* out      = (float*)d_out;
    float* wn       = (float*)d_ws;        // KCB floats
    float* partials = wn + KCB;            // BLOCKS floats

    hipLaunchKernelGGL(vq_wnorm, dim3(1), dim3(512), 0, stream, cb, wn);
    hipLaunchKernelGGL(vq_main, dim3(BLOCKS), dim3(THREADS), 0, stream,
                       x, cb, wn, out, partials);
    hipLaunchKernelGGL(vq_finalize, dim3(1), dim3(256), 0, stream,
                       partials, out + (size_t)N_ROWS * DIM);
}